// Round 3
// baseline (173.573 us; speedup 1.0000x reference)
//
#include <hip/hip_runtime.h>
#include <hip/hip_bf16.h>
#include <math.h>

#define NP 4096     // GRID*GRID
#define NA 256      // stim channels

typedef unsigned short ushort_t;
typedef __attribute__((ext_vector_type(8))) short short8;
typedef __attribute__((ext_vector_type(4))) float f32x4;
typedef __attribute__((ext_vector_type(4))) unsigned short ushort4v;
typedef __attribute__((ext_vector_type(8))) unsigned short ushort8v;

__device__ __forceinline__ ushort_t f2bf(float x) {
    __hip_bfloat16 h = __float2bfloat16(x);
    return *reinterpret_cast<ushort_t*>(&h);
}

// ---------------------------------------------------------------------------
// Fused setup: blocks 0..1023 build the Gaussian tables (4 p per block, one
// wave each); blocks 1024..1279 transpose stim -> bf16 stimT.
// gxn layout: [f][p][j]  (f32)   gyT layout: [f][gi][p]  (f32, transposed!)
// ---------------------------------------------------------------------------
__global__ __launch_bounds__(256)
void setup_all(const float* __restrict__ stim,
               const float* __restrict__ pscale,
               const float* __restrict__ pasig,
               const float* __restrict__ pagain,
               const float* __restrict__ pssf,
               const float* __restrict__ psff,
               float* __restrict__ gxn_all,
               float* __restrict__ gyT_all,
               float* __restrict__ attf,
               ushort_t* __restrict__ stimT)
{
    __shared__ float lt[64][65];
    int t = threadIdx.x;
    int bx = blockIdx.x;

    if (bx < 1024) {
        int p = bx * 4 + (t >> 6);
        int j = t & 63;
        const float step = 20.0f / 63.0f;
        float cx = -10.0f + step * (float)(p & 63);
        float cy = -10.0f + step * (float)(p >> 6);
        float coord = -10.0f + step * (float)j;

        float sig0 = 0.07f + pscale[0] * sqrtf(cx * cx + cy * cy);
        float fac1 = pssf[0], fac2 = psff[0];
        float dx = coord - cx, dy = coord - cy;

        #pragma unroll
        for (int f = 0; f < 3; ++f) {
            float s = sig0 * (f == 0 ? 1.0f : (f == 1 ? fac1 : fac2));
            float inv = 1.0f / (2.0f * s * s);
            float gx = expf(-dx * dx * inv);
            float gy = expf(-dy * dy * inv);
            float sx = gx, sy = gy;
            #pragma unroll
            for (int off = 32; off > 0; off >>= 1) {
                sx += __shfl_down(sx, off);
                sy += __shfl_down(sy, off);
            }
            sx = __shfl(sx, 0);
            sy = __shfl(sy, 0);
            gxn_all[(size_t)f * NP * 64 + (size_t)p * 64 + j] = gx / sx;
            gyT_all[(size_t)f * 64 * NP + (size_t)j * NP + p] = gy / sy;
        }
        if (j == 0) {
            float as = pasig[0];
            float d2 = (cx - 3.0f) * (cx - 3.0f) + cy * cy;
            attf[p] = pagain[0] * expf(-d2 / (2.0f * as * as)) + 1.0f;
        }
    } else {
        int b = bx - 1024;
        int g0 = (b & 63) * 64, a0 = (b >> 6) * 64;
        int ar = (t & 15) * 4, gr = t >> 4;
        #pragma unroll
        for (int k = 0; k < 4; ++k) {
            float4 v = *(const float4*)&stim[(size_t)(g0 + gr + 16 * k) * NA + a0 + ar];
            lt[gr + 16 * k][ar + 0] = v.x;
            lt[gr + 16 * k][ar + 1] = v.y;
            lt[gr + 16 * k][ar + 2] = v.z;
            lt[gr + 16 * k][ar + 3] = v.w;
        }
        __syncthreads();
        int a = t & 63, c = t >> 6;
        ushort8v u0, u1;
        #pragma unroll
        for (int i = 0; i < 8; ++i) u0[i] = f2bf(lt[c * 16 + i][a]);
        #pragma unroll
        for (int i = 0; i < 8; ++i) u1[i] = f2bf(lt[c * 16 + 8 + i][a]);
        ushort_t* dst = stimT + (size_t)(a0 + a) * NP + g0 + c * 16;
        *(ushort8v*)dst = u0;
        *(ushort8v*)(dst + 8) = u1;
    }
}

__device__ __forceinline__ short8 pack_row(const float* rp) {
    float4 v0 = *(const float4*)(rp);
    float4 v1 = *(const float4*)(rp + 4);
    short8 r;
    r[0] = (short)f2bf(v0.x); r[1] = (short)f2bf(v0.y);
    r[2] = (short)f2bf(v0.z); r[3] = (short)f2bf(v0.w);
    r[4] = (short)f2bf(v1.x); r[5] = (short)f2bf(v1.y);
    r[6] = (short)f2bf(v1.z); r[7] = (short)f2bf(v1.w);
    return r;
}

// ---------------------------------------------------------------------------
// C[p,a] = sum_g F[g,p]*B[g,a];  F[g,p] = gyT[g>>6][p]*gxn[p][g&63]
// Barrier-free: B-fragments read straight from global (L2-resident),
// register-pipelined 4 gi-steps deep. A-frags (gxn) constant over K in regs;
// gy applied to the per-gi MFMA partial in f32 (accumulator scaling).
// Block 512 thr = 8 waves = 4 n-groups x 2 fm-halves. Tile 64p x 64a.
// Grid (64,4) = 256 blocks. One __syncthreads total (lgyT stage).
// ---------------------------------------------------------------------------
template <int MODE>
__global__ __launch_bounds__(512)
void field_gemm(const float* __restrict__ gxn,   // [NP][64]
                const float* __restrict__ gyT,   // [64][NP]
                const ushort_t* __restrict__ bT, // [NA][NP] bf16
                const float* __restrict__ attf,
                const float* __restrict__ num,
                float* __restrict__ C,
                float* __restrict__ C2,
                ushort_t* __restrict__ CT)
{
    __shared__ float lgyT[64][64];   // [gi][p-local], 16 KB

    const int t   = threadIdx.x;
    const int w   = t >> 6;
    const int l   = t & 63;
    const int ng  = w >> 1;          // n-group 0..3
    const int fh  = w & 1;           // fm-half
    const int r16 = l & 15;
    const int q   = l >> 4;          // 0..3
    const int p0  = blockIdx.x * 64;
    const int a0  = blockIdx.y * 64;
    const int fbase = fh * 32;

    // coalesced lgyT stage (gyT is pre-transposed: rows contiguous in p)
    for (int idx = t; idx < 1024; idx += 512) {
        int gi = idx >> 4, c4 = idx & 15;
        ((f32x4*)&lgyT[gi][0])[c4] =
            ((const f32x4*)(gyT + (size_t)gi * NP + p0))[c4];
    }

    // A-fragments (constant over all K): rows p0+fbase+{0,16}+r16
    const float* r0 = gxn + (size_t)(p0 + fbase + r16) * 64;
    const float* r1 = gxn + (size_t)(p0 + fbase + 16 + r16) * 64;
    short8 ax00 = pack_row(r0 + q * 8);
    short8 ax01 = pack_row(r0 + 32 + q * 8);
    short8 ax10 = pack_row(r1 + q * 8);
    short8 ax11 = pack_row(r1 + 32 + q * 8);

    __syncthreads();

    const ushort_t* bbase = bT + (size_t)(a0 + ng * 16 + r16) * NP + q * 8;

    f32x4 acc0 = {0.f, 0.f, 0.f, 0.f};
    f32x4 acc1 = {0.f, 0.f, 0.f, 0.f};

#define LOADB(D0, D1, gi) {                                   \
        D0 = *(const short8*)(bbase + (gi) * 64);             \
        D1 = *(const short8*)(bbase + (gi) * 64 + 32); }

#define STEP(gi, B0, B1) {                                                     \
        f32x4 t0 = {0.f,0.f,0.f,0.f}, t1 = {0.f,0.f,0.f,0.f};                  \
        t0 = __builtin_amdgcn_mfma_f32_16x16x32_bf16(ax00, B0, t0, 0, 0, 0);   \
        t0 = __builtin_amdgcn_mfma_f32_16x16x32_bf16(ax01, B1, t0, 0, 0, 0);   \
        t1 = __builtin_amdgcn_mfma_f32_16x16x32_bf16(ax10, B0, t1, 0, 0, 0);   \
        t1 = __builtin_amdgcn_mfma_f32_16x16x32_bf16(ax11, B1, t1, 0, 0, 0);   \
        f32x4 s0 = *(const f32x4*)&lgyT[gi][fbase + q * 4];                    \
        f32x4 s1 = *(const f32x4*)&lgyT[gi][fbase + 16 + q * 4];               \
        acc0 += s0 * t0; acc1 += s1 * t1; }

    // 4-deep register pipeline over gi = 0..63, no barriers
    short8 pa0, pa1, pb0, pb1, pc0, pc1, pd0, pd1;
    LOADB(pa0, pa1, 0);
    LOADB(pb0, pb1, 1);
    LOADB(pc0, pc1, 2);
    LOADB(pd0, pd1, 3);
    for (int g4 = 0; g4 < 16; ++g4) {
        int gi = 4 * g4;
        STEP(gi + 0, pa0, pa1);
        if (g4 < 15) LOADB(pa0, pa1, gi + 4);
        STEP(gi + 1, pb0, pb1);
        if (g4 < 15) LOADB(pb0, pb1, gi + 5);
        STEP(gi + 2, pc0, pc1);
        if (g4 < 15) LOADB(pc0, pc1, gi + 6);
        STEP(gi + 3, pd0, pd1);
        if (g4 < 15) LOADB(pd0, pd1, gi + 7);
    }
#undef LOADB
#undef STEP

    // ---- epilogue (no cross-wave reduce: each wave owns full K) ----
    const int a   = a0 + ng * 16 + r16;
    const int prA = p0 + fbase + q * 4;       // acc0 rows prA..prA+3
    const int prB = prA + 16;                 // acc1 rows

    if (MODE == 0) {
        ushort4v tvA, tvB;
        #pragma unroll
        for (int r = 0; r < 4; ++r) {
            float vA = acc0[r] * attf[prA + r];
            float vB = acc1[r] * attf[prB + r];
            C[(size_t)(prA + r) * NA + a] = vA;
            C[(size_t)(prB + r) * NA + a] = vB;
            tvA[r] = f2bf(vA);
            tvB[r] = f2bf(vB);
        }
        *(ushort4v*)&CT[(size_t)a * NP + prA] = tvA;
        *(ushort4v*)&CT[(size_t)a * NP + prB] = tvB;
    } else if (MODE == 1) {
        ushort4v tvA, tvB;
        #pragma unroll
        for (int r = 0; r < 4; ++r) {
            float sA = acc0[r], sB = acc1[r];
            C[(size_t)(prA + r) * NA + a] = sA;                 // surround
            C[(size_t)(prB + r) * NA + a] = sB;
            float nA = num[(size_t)(prA + r) * NA + a];
            float nB = num[(size_t)(prB + r) * NA + a];
            float pA = nA / (sA + 0.5f);
            float pB = nB / (sB + 0.5f);
            C2[(size_t)(prA + r) * NA + a] = pA;                // pred_neural
            C2[(size_t)(prB + r) * NA + a] = pB;
            tvA[r] = f2bf(pA);
            tvB[r] = f2bf(pB);
        }
        *(ushort4v*)&CT[(size_t)a * NP + prA] = tvA;
        *(ushort4v*)&CT[(size_t)a * NP + prB] = tvB;
    } else {
        #pragma unroll
        for (int r = 0; r < 4; ++r) {
            C[(size_t)(prA + r) * NA + a] = acc0[r];            // pred_voxel
            C[(size_t)(prB + r) * NA + a] = acc1[r];
        }
    }
}

extern "C" void kernel_launch(void* const* d_in, const int* in_sizes, int n_in,
                              void* d_out, int out_size, void* d_ws, size_t ws_size,
                              hipStream_t stream)
{
    const float* stim   = (const float*)d_in[0];
    const float* pscale = (const float*)d_in[1];
    const float* pasig  = (const float*)d_in[2];
    const float* pagain = (const float*)d_in[3];
    const float* pssf   = (const float*)d_in[4];
    const float* psff   = (const float*)d_in[5];

    float* out  = (float*)d_out;
    float* num  = out;
    float* surr = out + (size_t)NP * NA;
    float* pn   = out + 2 * (size_t)NP * NA;
    float* pv   = out + 3 * (size_t)NP * NA;

    // ws layout
    float*    gxn_all = (float*)d_ws;                         // 3*NP*64 f32
    float*    gyT_all = gxn_all + 3 * (size_t)NP * 64;        // 3*64*NP f32
    float*    attf    = gyT_all + 3 * (size_t)NP * 64;        // NP f32
    ushort_t* stimT   = (ushort_t*)(attf + NP);               // NA*NP bf16
    ushort_t* numT    = stimT + (size_t)NA * NP;              // NA*NP bf16
    ushort_t* pnT     = numT + (size_t)NA * NP;               // NA*NP bf16

    setup_all<<<1280, 256, 0, stream>>>(stim, pscale, pasig, pagain, pssf, psff,
                                        gxn_all, gyT_all, attf, stimT);

    const float* gx0 = gxn_all;
    const float* gx1 = gxn_all + (size_t)NP * 64;
    const float* gx2 = gxn_all + 2 * (size_t)NP * 64;
    const float* gy0 = gyT_all;
    const float* gy1 = gyT_all + (size_t)64 * NP;
    const float* gy2 = gyT_all + 2 * (size_t)64 * NP;

    dim3 g(64, 4);
    field_gemm<0><<<g, 512, 0, stream>>>(gx0, gy0, stimT, attf, nullptr,
                                         num, nullptr, numT);
    field_gemm<1><<<g, 512, 0, stream>>>(gx1, gy1, numT, attf, num,
                                         surr, pn, pnT);
    field_gemm<2><<<g, 512, 0, stream>>>(gx2, gy2, pnT, attf, nullptr,
                                         pv, nullptr, nullptr);
}

// Round 4
// 89.436 us; speedup vs baseline: 1.9407x; 1.9407x over previous
//
#include <hip/hip_runtime.h>
#include <hip/hip_bf16.h>
#include <math.h>

#define NP 4096     // GRID*GRID
#define NA 256      // stim channels

typedef unsigned short ushort_t;
typedef __attribute__((ext_vector_type(8))) short short8;
typedef __attribute__((ext_vector_type(4))) float f32x4;
typedef __attribute__((ext_vector_type(4))) unsigned short ushort4v;
typedef __attribute__((ext_vector_type(8))) unsigned short ushort8v;

__device__ __forceinline__ ushort_t f2bf(float x) {
    __hip_bfloat16 h = __float2bfloat16(x);
    return *reinterpret_cast<ushort_t*>(&h);
}

// ---------------------------------------------------------------------------
// Fused setup: blocks 0..1023 build the Gaussian tables (4 p per block, one
// wave each); blocks 1024..1279 transpose stim -> bf16 stimT.
// gxn layout: [f][p][j]  (f32)   gyT layout: [f][gi][p]  (f32, transposed!)
// ---------------------------------------------------------------------------
__global__ __launch_bounds__(256)
void setup_all(const float* __restrict__ stim,
               const float* __restrict__ pscale,
               const float* __restrict__ pasig,
               const float* __restrict__ pagain,
               const float* __restrict__ pssf,
               const float* __restrict__ psff,
               float* __restrict__ gxn_all,
               float* __restrict__ gyT_all,
               float* __restrict__ attf,
               ushort_t* __restrict__ stimT)
{
    __shared__ float lt[64][65];
    int t = threadIdx.x;
    int bx = blockIdx.x;

    if (bx < 1024) {
        int p = bx * 4 + (t >> 6);
        int j = t & 63;
        const float step = 20.0f / 63.0f;
        float cx = -10.0f + step * (float)(p & 63);
        float cy = -10.0f + step * (float)(p >> 6);
        float coord = -10.0f + step * (float)j;

        float sig0 = 0.07f + pscale[0] * sqrtf(cx * cx + cy * cy);
        float fac1 = pssf[0], fac2 = psff[0];
        float dx = coord - cx, dy = coord - cy;

        #pragma unroll
        for (int f = 0; f < 3; ++f) {
            float s = sig0 * (f == 0 ? 1.0f : (f == 1 ? fac1 : fac2));
            float inv = 1.0f / (2.0f * s * s);
            float gx = expf(-dx * dx * inv);
            float gy = expf(-dy * dy * inv);
            float sx = gx, sy = gy;
            #pragma unroll
            for (int off = 32; off > 0; off >>= 1) {
                sx += __shfl_down(sx, off);
                sy += __shfl_down(sy, off);
            }
            sx = __shfl(sx, 0);
            sy = __shfl(sy, 0);
            gxn_all[(size_t)f * NP * 64 + (size_t)p * 64 + j] = gx / sx;
            gyT_all[(size_t)f * 64 * NP + (size_t)j * NP + p] = gy / sy;
        }
        if (j == 0) {
            float as = pasig[0];
            float d2 = (cx - 3.0f) * (cx - 3.0f) + cy * cy;
            attf[p] = pagain[0] * expf(-d2 / (2.0f * as * as)) + 1.0f;
        }
    } else {
        int b = bx - 1024;
        int g0 = (b & 63) * 64, a0 = (b >> 6) * 64;
        int ar = (t & 15) * 4, gr = t >> 4;
        #pragma unroll
        for (int k = 0; k < 4; ++k) {
            float4 v = *(const float4*)&stim[(size_t)(g0 + gr + 16 * k) * NA + a0 + ar];
            lt[gr + 16 * k][ar + 0] = v.x;
            lt[gr + 16 * k][ar + 1] = v.y;
            lt[gr + 16 * k][ar + 2] = v.z;
            lt[gr + 16 * k][ar + 3] = v.w;
        }
        __syncthreads();
        int a = t & 63, c = t >> 6;
        ushort8v u0, u1;
        #pragma unroll
        for (int i = 0; i < 8; ++i) u0[i] = f2bf(lt[c * 16 + i][a]);
        #pragma unroll
        for (int i = 0; i < 8; ++i) u1[i] = f2bf(lt[c * 16 + 8 + i][a]);
        ushort_t* dst = stimT + (size_t)(a0 + a) * NP + g0 + c * 16;
        *(ushort8v*)dst = u0;
        *(ushort8v*)(dst + 8) = u1;
    }
}

__device__ __forceinline__ short8 pack_row(const float* rp) {
    float4 v0 = *(const float4*)(rp);
    float4 v1 = *(const float4*)(rp + 4);
    short8 r;
    r[0] = (short)f2bf(v0.x); r[1] = (short)f2bf(v0.y);
    r[2] = (short)f2bf(v0.z); r[3] = (short)f2bf(v0.w);
    r[4] = (short)f2bf(v1.x); r[5] = (short)f2bf(v1.y);
    r[6] = (short)f2bf(v1.z); r[7] = (short)f2bf(v1.w);
    return r;
}

// ---------------------------------------------------------------------------
// C[p,a] = sum_g F[g,p]*B[g,a];  F[g,p] = gyT[g>>6][p]*gxn[p][g&63]
// R2 structure + T3/T4: triple-buffered global_load_lds staging, stage issued
// 1 iter ahead, counted s_waitcnt vmcnt(2) + raw s_barrier (vmcnt(0) only on
// the last iter). 8 waves = 4 n-groups x 2 K-halves. Tile 64p x 64a.
// Grid 256 blocks, XCD-clustered swizzle.
// ---------------------------------------------------------------------------
template <int MODE>
__global__ __launch_bounds__(512)
void field_gemm(const float* __restrict__ gxn,   // [NP][64]
                const float* __restrict__ gyT,   // [64][NP]
                const ushort_t* __restrict__ bT, // [NA][NP] bf16
                const float* __restrict__ attf,
                const float* __restrict__ num,
                float* __restrict__ C,
                float* __restrict__ C2,
                ushort_t* __restrict__ CT)
{
    // lB: [buf][kh-half][row n (64)][64 g] ushort; logical 16B slot s of row n
    // stored at phys slot s ^ (n&7).
    __shared__ ushort_t lB[3][2][64 * 64];   // 48 KB
    __shared__ float lgyT[64][64];           // 16 KB   [gi][p-local]
    __shared__ float lred[4 * 64 * 17];      // 17 KB   k-half reduce scratch

    const int t   = threadIdx.x;
    const int w   = t >> 6;
    const int l   = t & 63;
    const int ng  = w >> 1;          // 0..3
    const int kh  = w & 1;           // K-half (gi parity)
    const int r16 = l & 15;
    const int q   = l >> 4;          // 0..3

    // XCD-clustered bijective swizzle (256 blocks, 8 XCDs): each XCD sees
    // only 1 a-panel (512 KB of bT) -> L2-resident staging source.
    const int v   = blockIdx.x + 64 * blockIdx.y;
    const int lid = (v & 7) * 32 + (v >> 3);
    const int p0  = (lid & 63) * 64;
    const int a0  = (lid >> 6) * 64;

    // DMA stage: wave w stages rows w*8..w*8+7; LDS dest is linear
    // (uniform base + lane*16B); source carries the inverse swizzle.
    const int srow  = l >> 3;
    const int sslot = (l & 7) ^ (srow & 7);
#define STAGE(buf, tt)                                                         \
    _Pragma("unroll")                                                          \
    for (int h = 0; h < 2; ++h) {                                              \
        const ushort_t* src = bT + (size_t)(a0 + w * 8 + srow) * NP            \
                              + (2 * (tt) + h) * 64 + sslot * 8;               \
        ushort_t* dst = &lB[buf][h][(w * 8) * 64];                             \
        __builtin_amdgcn_global_load_lds(                                      \
            (const __attribute__((address_space(1))) unsigned int*)src,        \
            (__attribute__((address_space(3))) unsigned int*)dst, 16, 0, 0);   \
    }

    STAGE(0, 0);   // first tile in flight while we do the prologue

    // lgyT stage (gyT pre-transposed: contiguous in p -> coalesced)
    for (int idx = t; idx < 1024; idx += 512) {
        int gi = idx >> 4, c4 = idx & 15;
        ((f32x4*)&lgyT[gi][0])[c4] =
            ((const f32x4*)(gyT + (size_t)gi * NP + p0))[c4];
    }

    // A-fragments (constant over all K): ax[fm][c]
    short8 ax[4][2];
    #pragma unroll
    for (int fm = 0; fm < 4; ++fm) {
        const float* rowp = gxn + (size_t)(p0 + fm * 16 + r16) * 64;
        ax[fm][0] = pack_row(rowp + q * 8);
        ax[fm][1] = pack_row(rowp + 32 + q * 8);
    }

    __syncthreads();   // drains prologue vmem (incl. STAGE(0)) + lgyT writes

    const int n   = ng * 16 + r16;                       // this lane's B column
    const int bo0 = n * 64 + ((q ^ (n & 7)) * 8);        // chunk 0 (swizzled)
    const int bo1 = n * 64 + (((4 + q) ^ (n & 7)) * 8);  // chunk 1
    const ushort_t* lbase = &lB[0][kh][0];

    f32x4 acc[4];
    #pragma unroll
    for (int fm = 0; fm < 4; ++fm) acc[fm] = (f32x4){0.f, 0.f, 0.f, 0.f};

    for (int tt = 0; tt < 32; ++tt) {
        const int buf = tt % 3;
        if (tt < 31) {
            STAGE((tt + 1) % 3, tt + 1);
            asm volatile("s_waitcnt vmcnt(2)" ::: "memory");  // own stage(tt) landed
        } else {
            asm volatile("s_waitcnt vmcnt(0)" ::: "memory");  // tail drain
        }
        __builtin_amdgcn_s_barrier();    // stage(tt) visible block-wide

        const ushort_t* bb = lbase + buf * (2 * 64 * 64);
        short8 b0 = *(const short8*)(bb + bo0);
        short8 b1 = *(const short8*)(bb + bo1);
        const int gi = 2 * tt + kh;
        #pragma unroll
        for (int fm = 0; fm < 4; ++fm) {
            f32x4 t0 = {0.f, 0.f, 0.f, 0.f};
            t0 = __builtin_amdgcn_mfma_f32_16x16x32_bf16(ax[fm][0], b0, t0, 0, 0, 0);
            t0 = __builtin_amdgcn_mfma_f32_16x16x32_bf16(ax[fm][1], b1, t0, 0, 0, 0);
            f32x4 s = *(const f32x4*)&lgyT[gi][fm * 16 + q * 4];
            acc[fm] += s * t0;
        }
    }
#undef STAGE

    // ---- reduce the two K-halves ----
    if (kh == 1) {
        float* dst = &lred[(ng * 64 + l) * 17];
        #pragma unroll
        for (int fm = 0; fm < 4; ++fm)
            #pragma unroll
            for (int r = 0; r < 4; ++r) dst[fm * 4 + r] = acc[fm][r];
    }
    __syncthreads();
    if (kh == 0) {
        const float* src = &lred[(ng * 64 + l) * 17];
        #pragma unroll
        for (int fm = 0; fm < 4; ++fm)
            #pragma unroll
            for (int r = 0; r < 4; ++r) acc[fm][r] += src[fm * 4 + r];

        // ---- epilogue ----
        int a = a0 + ng * 16 + r16;
        #pragma unroll
        for (int fm = 0; fm < 4; ++fm) {
            int pr = p0 + fm * 16 + q * 4;
            if (MODE == 0) {
                ushort4v tv;
                #pragma unroll
                for (int r = 0; r < 4; ++r) {
                    float vv = acc[fm][r] * attf[pr + r];
                    C[(size_t)(pr + r) * NA + a] = vv;
                    tv[r] = f2bf(vv);
                }
                *(ushort4v*)&CT[(size_t)a * NP + pr] = tv;
            } else if (MODE == 1) {
                ushort4v tv;
                #pragma unroll
                for (int r = 0; r < 4; ++r) {
                    float sres = acc[fm][r];
                    C[(size_t)(pr + r) * NA + a] = sres;            // surround
                    float nv = num[(size_t)(pr + r) * NA + a];
                    float pnv = nv / (sres + 0.5f);
                    C2[(size_t)(pr + r) * NA + a] = pnv;            // pred_neural
                    tv[r] = f2bf(pnv);
                }
                *(ushort4v*)&CT[(size_t)a * NP + pr] = tv;
            } else {
                #pragma unroll
                for (int r = 0; r < 4; ++r)
                    C[(size_t)(pr + r) * NA + a] = acc[fm][r];      // pred_voxel
            }
        }
    }
}

extern "C" void kernel_launch(void* const* d_in, const int* in_sizes, int n_in,
                              void* d_out, int out_size, void* d_ws, size_t ws_size,
                              hipStream_t stream)
{
    const float* stim   = (const float*)d_in[0];
    const float* pscale = (const float*)d_in[1];
    const float* pasig  = (const float*)d_in[2];
    const float* pagain = (const float*)d_in[3];
    const float* pssf   = (const float*)d_in[4];
    const float* psff   = (const float*)d_in[5];

    float* out  = (float*)d_out;
    float* num  = out;
    float* surr = out + (size_t)NP * NA;
    float* pn   = out + 2 * (size_t)NP * NA;
    float* pv   = out + 3 * (size_t)NP * NA;

    // ws layout
    float*    gxn_all = (float*)d_ws;                         // 3*NP*64 f32
    float*    gyT_all = gxn_all + 3 * (size_t)NP * 64;        // 3*64*NP f32
    float*    attf    = gyT_all + 3 * (size_t)NP * 64;        // NP f32
    ushort_t* stimT   = (ushort_t*)(attf + NP);               // NA*NP bf16
    ushort_t* numT    = stimT + (size_t)NA * NP;              // NA*NP bf16
    ushort_t* pnT     = numT + (size_t)NA * NP;               // NA*NP bf16

    setup_all<<<1280, 256, 0, stream>>>(stim, pscale, pasig, pagain, pssf, psff,
                                        gxn_all, gyT_all, attf, stimT);

    const float* gx0 = gxn_all;
    const float* gx1 = gxn_all + (size_t)NP * 64;
    const float* gx2 = gxn_all + 2 * (size_t)NP * 64;
    const float* gy0 = gyT_all;
    const float* gy1 = gyT_all + (size_t)64 * NP;
    const float* gy2 = gyT_all + 2 * (size_t)64 * NP;

    dim3 g(64, 4);
    field_gemm<0><<<g, 512, 0, stream>>>(gx0, gy0, stimT, attf, nullptr,
                                         num, nullptr, numT);
    field_gemm<1><<<g, 512, 0, stream>>>(gx1, gy1, numT, attf, num,
                                         surr, pn, pnT);
    field_gemm<2><<<g, 512, 0, stream>>>(gx2, gy2, pnT, attf, nullptr,
                                         pv, nullptr, nullptr);
}

// Round 5
// 77.630 us; speedup vs baseline: 2.2359x; 1.1521x over previous
//
#include <hip/hip_runtime.h>
#include <hip/hip_bf16.h>
#include <math.h>

#define NP 4096     // GRID*GRID
#define NA 256      // stim channels

typedef unsigned short ushort_t;
typedef __attribute__((ext_vector_type(8))) short short8;
typedef __attribute__((ext_vector_type(4))) float f32x4;
typedef __attribute__((ext_vector_type(8))) unsigned short ushort8v;

__device__ __forceinline__ ushort_t f2bf(float x) {
    __hip_bfloat16 h = __float2bfloat16(x);
    return *reinterpret_cast<ushort_t*>(&h);
}

// ---------------------------------------------------------------------------
// Fused setup, 448 blocks x 256 thr:
//  blocks [0,192): field f = bx>>6, p-tile pb = bx&63. Computes gxn (coalesced)
//                  and gyT via an LDS tile (coalesced output writes).
//  blocks [192,448): transpose stim [4096 g][256 a] f32 -> stimT [256][4096] bf16
// gxn layout: [f][p][j]  f32;  gyT layout: [f][gi][p]  f32 (transposed).
// ---------------------------------------------------------------------------
__global__ __launch_bounds__(256)
void setup_all(const float* __restrict__ stim,
               const float* __restrict__ pscale,
               const float* __restrict__ pasig,
               const float* __restrict__ pagain,
               const float* __restrict__ pssf,
               const float* __restrict__ psff,
               float* __restrict__ gxn_all,
               float* __restrict__ gyT_all,
               float* __restrict__ attf,
               ushort_t* __restrict__ stimT)
{
    __shared__ float lt[64][65];
    const int t = threadIdx.x;
    const int bx = blockIdx.x;
    const float step = 20.0f / 63.0f;

    if (bx < 192) {
        const int f  = bx >> 6;
        const int pb = bx & 63;
        const int j  = t & 63;          // lane = x/y sample index
        const int w  = t >> 6;          // wave 0..3
        const float fac = (f == 0) ? 1.0f : (f == 1 ? pssf[0] : psff[0]);
        const float coord = -10.0f + step * (float)j;

        for (int pass = 0; pass < 16; ++pass) {
            const int pl = pass * 4 + w;
            const int p  = pb * 64 + pl;
            float cx = -10.0f + step * (float)(p & 63);
            float cy = -10.0f + step * (float)(p >> 6);
            float sig0 = 0.07f + pscale[0] * sqrtf(cx * cx + cy * cy);
            float s = sig0 * fac;
            float inv = 1.0f / (2.0f * s * s);
            float dx = coord - cx, dy = coord - cy;
            float gx = expf(-dx * dx * inv);
            float gy = expf(-dy * dy * inv);
            float sx = gx, sy = gy;
            #pragma unroll
            for (int off = 32; off > 0; off >>= 1) {
                sx += __shfl_down(sx, off);
                sy += __shfl_down(sy, off);
            }
            sx = __shfl(sx, 0);
            sy = __shfl(sy, 0);
            gxn_all[(size_t)f * NP * 64 + (size_t)p * 64 + j] = gx / sx;
            lt[j][pl] = gy / sy;
            if (f == 0 && j == 0) {
                float as = pasig[0];
                float d2 = (cx - 3.0f) * (cx - 3.0f) + cy * cy;
                attf[p] = pagain[0] * expf(-d2 / (2.0f * as * as)) + 1.0f;
            }
        }
        __syncthreads();
        // coalesced gyT writes: row r (=gi), 64 consecutive p
        for (int idx = t; idx < 4096; idx += 256) {
            int r = idx >> 6, c = idx & 63;
            gyT_all[(size_t)f * 64 * NP + (size_t)r * NP + pb * 64 + c] = lt[r][c];
        }
    } else {
        const int b = bx - 192;
        const int g0 = (b & 63) * 64, a0 = (b >> 6) * 64;
        const int ar = (t & 15) * 4, gr = t >> 4;
        #pragma unroll
        for (int k = 0; k < 4; ++k) {
            float4 v = *(const float4*)&stim[(size_t)(g0 + gr + 16 * k) * NA + a0 + ar];
            lt[gr + 16 * k][ar + 0] = v.x;
            lt[gr + 16 * k][ar + 1] = v.y;
            lt[gr + 16 * k][ar + 2] = v.z;
            lt[gr + 16 * k][ar + 3] = v.w;
        }
        __syncthreads();
        const int a = t & 63, c = t >> 6;
        ushort8v u0, u1;
        #pragma unroll
        for (int i = 0; i < 8; ++i) u0[i] = f2bf(lt[c * 16 + i][a]);
        #pragma unroll
        for (int i = 0; i < 8; ++i) u1[i] = f2bf(lt[c * 16 + 8 + i][a]);
        ushort_t* dst = stimT + (size_t)(a0 + a) * NP + g0 + c * 16;
        *(ushort8v*)dst = u0;
        *(ushort8v*)(dst + 8) = u1;
    }
}

__device__ __forceinline__ short8 pack_row(const float* rp) {
    float4 v0 = *(const float4*)(rp);
    float4 v1 = *(const float4*)(rp + 4);
    short8 r;
    r[0] = (short)f2bf(v0.x); r[1] = (short)f2bf(v0.y);
    r[2] = (short)f2bf(v0.z); r[3] = (short)f2bf(v0.w);
    r[4] = (short)f2bf(v1.x); r[5] = (short)f2bf(v1.y);
    r[6] = (short)f2bf(v1.z); r[7] = (short)f2bf(v1.w);
    return r;
}

// ---------------------------------------------------------------------------
// Transposed-output GEMM:  C^T[a,p] = sum_g B[g,a] * gy[p][gi] * gx[p][gj]
//   MFMA A-operand  = stim rows (a x k) from XOR-swizzled LDS (2 x b128/gi)
//   MFMA B-operand  = gxn fragments, K-invariant, in REGISTERS (free)
//   gy scale: output col = p -> per-lane SCALAR; permuted LDS layout
//             lgy2[gi][r16][pt] makes it ONE ds_read_b128 (4-way bcast)/gi.
// 8 waves = 4 a-subtiles x 2 K-halves. Tile 64p x 64a. Grid 256, XCD swizzle.
// Triple-buffered global_load_lds staging, counted vmcnt(2), s_setprio MFMA.
// lred aliased onto dead lB after the K-loop (LDS 64 KB total).
// MODE 0: C=dot*attf[p] (num), CT=bf16^T;  MODE 1: C=surr, C2=num/(surr+.5)
// (pn), CT=bf16(pn)^T;  MODE 2: C=dot (pv).
// ---------------------------------------------------------------------------
template <int MODE>
__global__ __launch_bounds__(512)
void field_gemm(const float* __restrict__ gxn,   // [NP][64]
                const float* __restrict__ gyT,   // [64][NP]
                const ushort_t* __restrict__ bT, // [NA][NP] bf16
                const float* __restrict__ attf,
                const float* __restrict__ num,
                float* __restrict__ C,
                float* __restrict__ C2,
                ushort_t* __restrict__ CT)
{
    __shared__ __align__(16) unsigned char smem[65536];
    ushort_t* lB   = (ushort_t*)smem;             // [3 buf][2 half][64 a][64 g]
    float*    lgy2 = (float*)(smem + 49152);      // [64 gi][16 r16][4 pt]
    float*    lred = (float*)smem;                // alias of lB (post-loop)

    const int t    = threadIdx.x;
    const int w    = t >> 6;
    const int l    = t & 63;
    const int asub = w >> 1;         // 0..3  (a-subtile)
    const int kh   = w & 1;          // K-half (gi parity)
    const int r16  = l & 15;
    const int q    = l >> 4;         // 0..3

    // XCD-clustered bijective swizzle (256 blocks, 8 XCDs)
    const int v   = blockIdx.x + 64 * blockIdx.y;
    const int lid = (v & 7) * 32 + (v >> 3);
    const int p0  = (lid & 63) * 64;
    const int a0  = (lid >> 6) * 64;

    const int srow  = l >> 3;
    const int sslot = (l & 7) ^ (srow & 7);
#define STAGE(buf, tt)                                                         \
    _Pragma("unroll")                                                          \
    for (int h = 0; h < 2; ++h) {                                              \
        const ushort_t* src = bT + (size_t)(a0 + w * 8 + srow) * NP            \
                              + (2 * (tt) + h) * 64 + sslot * 8;               \
        ushort_t* dst = lB + ((buf) * 2 + h) * 4096 + (w * 8) * 64;            \
        __builtin_amdgcn_global_load_lds(                                      \
            (const __attribute__((address_space(1))) unsigned int*)src,        \
            (__attribute__((address_space(3))) unsigned int*)dst, 16, 0, 0);   \
    }

    STAGE(0, 0);   // first tile in flight during prologue

    // lgy2 stage: permuted [gi][r16][pt] so the K-loop reads ONE b128/gi
    for (int idx = t; idx < 4096; idx += 512) {
        int gi = idx >> 6, pl = idx & 63;
        lgy2[gi * 64 + (pl & 15) * 4 + (pl >> 4)] =
            gyT[(size_t)gi * NP + p0 + pl];
    }

    // B-operand fragments (gxn), K-invariant: gxf[pt][c]
    short8 gxf[4][2];
    #pragma unroll
    for (int pt = 0; pt < 4; ++pt) {
        const float* rowp = gxn + (size_t)(p0 + pt * 16 + r16) * 64;
        gxf[pt][0] = pack_row(rowp + q * 8);
        gxf[pt][1] = pack_row(rowp + 32 + q * 8);
    }

    __syncthreads();   // drains STAGE(0) + lgy2 writes

    const int n   = asub * 16 + r16;                     // A-row (a_local)
    const int bo0 = n * 64 + ((q ^ (n & 7)) * 8);        // k 0..31 (swizzled)
    const int bo1 = n * 64 + (((4 + q) ^ (n & 7)) * 8);  // k 32..63

    f32x4 acc[4];
    #pragma unroll
    for (int pt = 0; pt < 4; ++pt) acc[pt] = (f32x4){0.f, 0.f, 0.f, 0.f};

    for (int tt = 0; tt < 32; ++tt) {
        const int buf = tt % 3;
        if (tt < 31) {
            STAGE((tt + 1) % 3, tt + 1);
            asm volatile("s_waitcnt vmcnt(2)" ::: "memory");
        } else {
            asm volatile("s_waitcnt vmcnt(0)" ::: "memory");
        }
        __builtin_amdgcn_s_barrier();

        const ushort_t* bb = lB + (buf * 2 + kh) * 4096;
        short8 A0 = *(const short8*)(bb + bo0);
        short8 A1 = *(const short8*)(bb + bo1);
        const int gi = 2 * tt + kh;
        f32x4 s4 = *(const f32x4*)(lgy2 + gi * 64 + r16 * 4);

        __builtin_amdgcn_s_setprio(1);
        #pragma unroll
        for (int pt = 0; pt < 4; ++pt) {
            f32x4 tmp = (f32x4){0.f, 0.f, 0.f, 0.f};
            tmp = __builtin_amdgcn_mfma_f32_16x16x32_bf16(A0, gxf[pt][0], tmp, 0, 0, 0);
            tmp = __builtin_amdgcn_mfma_f32_16x16x32_bf16(A1, gxf[pt][1], tmp, 0, 0, 0);
            float sc = s4[pt];
            acc[pt] += tmp * sc;
        }
        __builtin_amdgcn_s_setprio(0);
    }
#undef STAGE

    // ---- reduce the two K-halves (lred aliases dead lB) ----
    __syncthreads();   // all lB reads done before aliasing
    if (kh == 1) {
        float* dst = lred + (asub * 64 + l) * 17;
        #pragma unroll
        for (int pt = 0; pt < 4; ++pt)
            #pragma unroll
            for (int r = 0; r < 4; ++r) dst[pt * 4 + r] = acc[pt][r];
    }
    __syncthreads();
    if (kh == 0) {
        const float* src = lred + (asub * 64 + l) * 17;
        #pragma unroll
        for (int pt = 0; pt < 4; ++pt)
            #pragma unroll
            for (int r = 0; r < 4; ++r) acc[pt][r] += src[pt * 4 + r];

        // ---- epilogue: lane owns col p (per pt), rows abase..abase+3 ----
        const int abase = a0 + asub * 16 + q * 4;
        #pragma unroll
        for (int pt = 0; pt < 4; ++pt) {
            const int p = p0 + pt * 16 + r16;
            f32x4 vv = acc[pt];
            if (MODE == 0) {
                float att = attf[p];
                vv *= att;
                *(f32x4*)(C + (size_t)p * NA + abase) = vv;
                #pragma unroll
                for (int r = 0; r < 4; ++r)
                    CT[(size_t)(abase + r) * NP + p] = f2bf(vv[r]);
            } else if (MODE == 1) {
                *(f32x4*)(C + (size_t)p * NA + abase) = vv;      // surround
                f32x4 nv = *(const f32x4*)(num + (size_t)p * NA + abase);
                f32x4 pnv = nv / (vv + 0.5f);
                *(f32x4*)(C2 + (size_t)p * NA + abase) = pnv;    // pred_neural
                #pragma unroll
                for (int r = 0; r < 4; ++r)
                    CT[(size_t)(abase + r) * NP + p] = f2bf(pnv[r]);
            } else {
                *(f32x4*)(C + (size_t)p * NA + abase) = vv;      // pred_voxel
            }
        }
    }
}

extern "C" void kernel_launch(void* const* d_in, const int* in_sizes, int n_in,
                              void* d_out, int out_size, void* d_ws, size_t ws_size,
                              hipStream_t stream)
{
    const float* stim   = (const float*)d_in[0];
    const float* pscale = (const float*)d_in[1];
    const float* pasig  = (const float*)d_in[2];
    const float* pagain = (const float*)d_in[3];
    const float* pssf   = (const float*)d_in[4];
    const float* psff   = (const float*)d_in[5];

    float* out  = (float*)d_out;
    float* num  = out;
    float* surr = out + (size_t)NP * NA;
    float* pn   = out + 2 * (size_t)NP * NA;
    float* pv   = out + 3 * (size_t)NP * NA;

    // ws layout
    float*    gxn_all = (float*)d_ws;                         // 3*NP*64 f32
    float*    gyT_all = gxn_all + 3 * (size_t)NP * 64;        // 3*64*NP f32
    float*    attf    = gyT_all + 3 * (size_t)NP * 64;        // NP f32
    ushort_t* stimT   = (ushort_t*)(attf + NP);               // NA*NP bf16
    ushort_t* numT    = stimT + (size_t)NA * NP;              // NA*NP bf16
    ushort_t* pnT     = numT + (size_t)NA * NP;               // NA*NP bf16

    setup_all<<<448, 256, 0, stream>>>(stim, pscale, pasig, pagain, pssf, psff,
                                       gxn_all, gyT_all, attf, stimT);

    const float* gx0 = gxn_all;
    const float* gx1 = gxn_all + (size_t)NP * 64;
    const float* gx2 = gxn_all + 2 * (size_t)NP * 64;
    const float* gy0 = gyT_all;
    const float* gy1 = gyT_all + (size_t)64 * NP;
    const float* gy2 = gyT_all + 2 * (size_t)64 * NP;

    dim3 g(64, 4);
    field_gemm<0><<<g, 512, 0, stream>>>(gx0, gy0, stimT, attf, nullptr,
                                         num, nullptr, numT);
    field_gemm<1><<<g, 512, 0, stream>>>(gx1, gy1, numT, attf, num,
                                         surr, pn, pnT);
    field_gemm<2><<<g, 512, 0, stream>>>(gx2, gy2, pnT, attf, nullptr,
                                         pv, nullptr, nullptr);
}

// Round 6
// 75.470 us; speedup vs baseline: 2.2999x; 1.0286x over previous
//
#include <hip/hip_runtime.h>
#include <hip/hip_bf16.h>
#include <math.h>

#define NP 4096     // GRID*GRID
#define NA 256      // stim channels

typedef unsigned short ushort_t;
typedef __attribute__((ext_vector_type(8))) short short8;
typedef __attribute__((ext_vector_type(4))) float f32x4;
typedef __attribute__((ext_vector_type(8))) unsigned short ushort8v;

__device__ __forceinline__ ushort_t f2bf(float x) {
    __hip_bfloat16 h = __float2bfloat16(x);
    return *reinterpret_cast<ushort_t*>(&h);
}

// ---------------------------------------------------------------------------
// Fused setup, 448 blocks x 256 thr:
//  blocks [0,192): field f = bx>>6, p-tile pb = bx&63. Computes gxn (coalesced)
//                  and gyT via an LDS tile (coalesced output writes).
//  blocks [192,448): transpose stim [4096 g][256 a] f32 -> stimT [256][4096] bf16
// gxn layout: [f][p][j]  f32;  gyT layout: [f][gi][p]  f32 (transposed).
// ---------------------------------------------------------------------------
__global__ __launch_bounds__(256)
void setup_all(const float* __restrict__ stim,
               const float* __restrict__ pscale,
               const float* __restrict__ pasig,
               const float* __restrict__ pagain,
               const float* __restrict__ pssf,
               const float* __restrict__ psff,
               float* __restrict__ gxn_all,
               float* __restrict__ gyT_all,
               float* __restrict__ attf,
               ushort_t* __restrict__ stimT)
{
    __shared__ float lt[64][65];
    const int t = threadIdx.x;
    const int bx = blockIdx.x;
    const float step = 20.0f / 63.0f;

    if (bx < 192) {
        const int f  = bx >> 6;
        const int pb = bx & 63;
        const int j  = t & 63;          // lane = x/y sample index
        const int w  = t >> 6;          // wave 0..3
        const float fac = (f == 0) ? 1.0f : (f == 1 ? pssf[0] : psff[0]);
        const float coord = -10.0f + step * (float)j;

        for (int pass = 0; pass < 16; ++pass) {
            const int pl = pass * 4 + w;
            const int p  = pb * 64 + pl;
            float cx = -10.0f + step * (float)(p & 63);
            float cy = -10.0f + step * (float)(p >> 6);
            float sig0 = 0.07f + pscale[0] * sqrtf(cx * cx + cy * cy);
            float s = sig0 * fac;
            float inv = 1.0f / (2.0f * s * s);
            float dx = coord - cx, dy = coord - cy;
            float gx = expf(-dx * dx * inv);
            float gy = expf(-dy * dy * inv);
            float sx = gx, sy = gy;
            #pragma unroll
            for (int off = 32; off > 0; off >>= 1) {
                sx += __shfl_down(sx, off);
                sy += __shfl_down(sy, off);
            }
            sx = __shfl(sx, 0);
            sy = __shfl(sy, 0);
            gxn_all[(size_t)f * NP * 64 + (size_t)p * 64 + j] = gx / sx;
            lt[j][pl] = gy / sy;
            if (f == 0 && j == 0) {
                float as = pasig[0];
                float d2 = (cx - 3.0f) * (cx - 3.0f) + cy * cy;
                attf[p] = pagain[0] * expf(-d2 / (2.0f * as * as)) + 1.0f;
            }
        }
        __syncthreads();
        // coalesced gyT writes: row r (=gi), 64 consecutive p
        for (int idx = t; idx < 4096; idx += 256) {
            int r = idx >> 6, c = idx & 63;
            gyT_all[(size_t)f * 64 * NP + (size_t)r * NP + pb * 64 + c] = lt[r][c];
        }
    } else {
        const int b = bx - 192;
        const int g0 = (b & 63) * 64, a0 = (b >> 6) * 64;
        const int ar = (t & 15) * 4, gr = t >> 4;
        #pragma unroll
        for (int k = 0; k < 4; ++k) {
            float4 v = *(const float4*)&stim[(size_t)(g0 + gr + 16 * k) * NA + a0 + ar];
            lt[gr + 16 * k][ar + 0] = v.x;
            lt[gr + 16 * k][ar + 1] = v.y;
            lt[gr + 16 * k][ar + 2] = v.z;
            lt[gr + 16 * k][ar + 3] = v.w;
        }
        __syncthreads();
        const int a = t & 63, c = t >> 6;
        ushort8v u0, u1;
        #pragma unroll
        for (int i = 0; i < 8; ++i) u0[i] = f2bf(lt[c * 16 + i][a]);
        #pragma unroll
        for (int i = 0; i < 8; ++i) u1[i] = f2bf(lt[c * 16 + 8 + i][a]);
        ushort_t* dst = stimT + (size_t)(a0 + a) * NP + g0 + c * 16;
        *(ushort8v*)dst = u0;
        *(ushort8v*)(dst + 8) = u1;
    }
}

__device__ __forceinline__ short8 pack_row(const float* rp) {
    float4 v0 = *(const float4*)(rp);
    float4 v1 = *(const float4*)(rp + 4);
    short8 r;
    r[0] = (short)f2bf(v0.x); r[1] = (short)f2bf(v0.y);
    r[2] = (short)f2bf(v0.z); r[3] = (short)f2bf(v0.w);
    r[4] = (short)f2bf(v1.x); r[5] = (short)f2bf(v1.y);
    r[6] = (short)f2bf(v1.z); r[7] = (short)f2bf(v1.w);
    return r;
}

// ---------------------------------------------------------------------------
// Transposed-output GEMM:  C^T[a,p] = sum_g B[g,a] * gy[p][gi] * gx[p][gj]
//   MFMA A-operand  = stim rows (a x k) from XOR-swizzled LDS (2 x b128/gi)
//   MFMA B-operand  = gxn fragments, K-invariant, in REGISTERS (free)
//   gy scale: output col = p -> per-lane SCALAR; permuted LDS layout
//             lgy2[gi][r16][pt] = ONE ds_read_b128 (4-way bcast)/gi.
// Deep pipeline: NBUF=8 (128 KB), 2 tt per barrier phase (16 barriers),
// stage 2 tiles/phase issued 2 phases (4 tiles) ahead, counted vmcnt(8)
// (4/0 in the tail). Stage->overwrite target is the buffer read 2 phases
// ago; one barrier/phase bounds wave skew -> race-free.
// 8 waves = 4 a-subtiles x 2 K-halves. Tile 64p x 64a. Grid 256, XCD swizzle.
// MODE 0: C=dot*attf[p] (num), CT=bf16^T;  MODE 1: C=surr, C2=num/(surr+.5)
// (pn), CT=bf16(pn)^T;  MODE 2: C=dot (pv).
// ---------------------------------------------------------------------------
template <int MODE>
__global__ __launch_bounds__(512)
void field_gemm(const float* __restrict__ gxn,   // [NP][64]
                const float* __restrict__ gyT,   // [64][NP]
                const ushort_t* __restrict__ bT, // [NA][NP] bf16
                const float* __restrict__ attf,
                const float* __restrict__ num,
                float* __restrict__ C,
                float* __restrict__ C2,
                ushort_t* __restrict__ CT)
{
    __shared__ __align__(16) unsigned char smem[147456];
    ushort_t* lB   = (ushort_t*)smem;             // [8 buf][2 half][64 a][64 g]
    float*    lgy2 = (float*)(smem + 131072);     // [64 gi][16 r16][4 pt]
    float*    lred = (float*)smem;                // alias of lB (post-loop)

    const int t    = threadIdx.x;
    const int w    = t >> 6;
    const int l    = t & 63;
    const int asub = w >> 1;         // 0..3  (a-subtile)
    const int kh   = w & 1;          // K-half (gi parity)
    const int r16  = l & 15;
    const int q    = l >> 4;         // 0..3

    // XCD-clustered bijective swizzle (256 blocks, 8 XCDs)
    const int v   = blockIdx.x + 64 * blockIdx.y;
    const int lid = (v & 7) * 32 + (v >> 3);
    const int p0  = (lid & 63) * 64;
    const int a0  = (lid >> 6) * 64;

    const int srow  = l >> 3;
    const int sslot = (l & 7) ^ (srow & 7);
#define STAGE(buf, tt)                                                         \
    _Pragma("unroll")                                                          \
    for (int h = 0; h < 2; ++h) {                                              \
        const ushort_t* src = bT + (size_t)(a0 + w * 8 + srow) * NP            \
                              + (2 * (tt) + h) * 64 + sslot * 8;               \
        ushort_t* dst = lB + ((buf) * 2 + h) * 4096 + (w * 8) * 64;            \
        __builtin_amdgcn_global_load_lds(                                      \
            (const __attribute__((address_space(1))) unsigned int*)src,        \
            (__attribute__((address_space(3))) unsigned int*)dst, 16, 0, 0);   \
    }

    // prologue: 4 tiles in flight while we build tables
    STAGE(0, 0); STAGE(1, 1); STAGE(2, 2); STAGE(3, 3);

    // lgy2 stage: permuted [gi][r16][pt] so the K-loop reads ONE b128/gi
    for (int idx = t; idx < 4096; idx += 512) {
        int gi = idx >> 6, pl = idx & 63;
        lgy2[gi * 64 + (pl & 15) * 4 + (pl >> 4)] =
            gyT[(size_t)gi * NP + p0 + pl];
    }

    // B-operand fragments (gxn), K-invariant: gxf[pt][c]
    short8 gxf[4][2];
    #pragma unroll
    for (int pt = 0; pt < 4; ++pt) {
        const float* rowp = gxn + (size_t)(p0 + pt * 16 + r16) * 64;
        gxf[pt][0] = pack_row(rowp + q * 8);
        gxf[pt][1] = pack_row(rowp + 32 + q * 8);
    }

    __syncthreads();   // drains prologue DMA + lgy2 writes (vmcnt -> 0 here)

    const int n   = asub * 16 + r16;                     // A-row (a_local)
    const int bo0 = n * 64 + ((q ^ (n & 7)) * 8);        // k 0..31 (swizzled)
    const int bo1 = n * 64 + (((4 + q) ^ (n & 7)) * 8);  // k 32..63

    f32x4 acc[4];
    #pragma unroll
    for (int pt = 0; pt < 4; ++pt) acc[pt] = (f32x4){0.f, 0.f, 0.f, 0.f};

    for (int ph = 0; ph < 16; ++ph) {
        if (ph <= 13) {
            STAGE((2 * ph + 4) & 7, 2 * ph + 4);
            STAGE((2 * ph + 5) & 7, 2 * ph + 5);
            asm volatile("s_waitcnt vmcnt(8)" ::: "memory");   // tt=2ph,2ph+1 landed
        } else if (ph == 14) {
            asm volatile("s_waitcnt vmcnt(4)" ::: "memory");
        } else {
            asm volatile("s_waitcnt vmcnt(0)" ::: "memory");
        }
        __builtin_amdgcn_s_barrier();

        #pragma unroll
        for (int u = 0; u < 2; ++u) {
            const int tt = 2 * ph + u;
            const ushort_t* bb = lB + ((tt & 7) * 2 + kh) * 4096;
            short8 A0 = *(const short8*)(bb + bo0);
            short8 A1 = *(const short8*)(bb + bo1);
            const int gi = 2 * tt + kh;
            f32x4 s4 = *(const f32x4*)(lgy2 + gi * 64 + r16 * 4);

            __builtin_amdgcn_s_setprio(1);
            #pragma unroll
            for (int pt = 0; pt < 4; ++pt) {
                f32x4 tmp = (f32x4){0.f, 0.f, 0.f, 0.f};
                tmp = __builtin_amdgcn_mfma_f32_16x16x32_bf16(A0, gxf[pt][0], tmp, 0, 0, 0);
                tmp = __builtin_amdgcn_mfma_f32_16x16x32_bf16(A1, gxf[pt][1], tmp, 0, 0, 0);
                float sc = s4[pt];
                acc[pt] += tmp * sc;
            }
            __builtin_amdgcn_s_setprio(0);
        }
    }
#undef STAGE

    // ---- reduce the two K-halves (lred aliases dead lB) ----
    __syncthreads();   // all lB reads done before aliasing
    if (kh == 1) {
        float* dst = lred + (asub * 64 + l) * 17;
        #pragma unroll
        for (int pt = 0; pt < 4; ++pt)
            #pragma unroll
            for (int r = 0; r < 4; ++r) dst[pt * 4 + r] = acc[pt][r];
    }
    __syncthreads();
    if (kh == 0) {
        const float* src = lred + (asub * 64 + l) * 17;
        #pragma unroll
        for (int pt = 0; pt < 4; ++pt)
            #pragma unroll
            for (int r = 0; r < 4; ++r) acc[pt][r] += src[pt * 4 + r];

        // ---- epilogue: lane owns col p (per pt), rows abase..abase+3 ----
        const int abase = a0 + asub * 16 + q * 4;
        #pragma unroll
        for (int pt = 0; pt < 4; ++pt) {
            const int p = p0 + pt * 16 + r16;
            f32x4 vv = acc[pt];
            if (MODE == 0) {
                float att = attf[p];
                vv *= att;
                *(f32x4*)(C + (size_t)p * NA + abase) = vv;
                #pragma unroll
                for (int r = 0; r < 4; ++r)
                    CT[(size_t)(abase + r) * NP + p] = f2bf(vv[r]);
            } else if (MODE == 1) {
                *(f32x4*)(C + (size_t)p * NA + abase) = vv;      // surround
                f32x4 nv = *(const f32x4*)(num + (size_t)p * NA + abase);
                f32x4 pnv = nv / (vv + 0.5f);
                *(f32x4*)(C2 + (size_t)p * NA + abase) = pnv;    // pred_neural
                #pragma unroll
                for (int r = 0; r < 4; ++r)
                    CT[(size_t)(abase + r) * NP + p] = f2bf(pnv[r]);
            } else {
                *(f32x4*)(C + (size_t)p * NA + abase) = vv;      // pred_voxel
            }
        }
    }
}

extern "C" void kernel_launch(void* const* d_in, const int* in_sizes, int n_in,
                              void* d_out, int out_size, void* d_ws, size_t ws_size,
                              hipStream_t stream)
{
    const float* stim   = (const float*)d_in[0];
    const float* pscale = (const float*)d_in[1];
    const float* pasig  = (const float*)d_in[2];
    const float* pagain = (const float*)d_in[3];
    const float* pssf   = (const float*)d_in[4];
    const float* psff   = (const float*)d_in[5];

    float* out  = (float*)d_out;
    float* num  = out;
    float* surr = out + (size_t)NP * NA;
    float* pn   = out + 2 * (size_t)NP * NA;
    float* pv   = out + 3 * (size_t)NP * NA;

    // ws layout
    float*    gxn_all = (float*)d_ws;                         // 3*NP*64 f32
    float*    gyT_all = gxn_all + 3 * (size_t)NP * 64;        // 3*64*NP f32
    float*    attf    = gyT_all + 3 * (size_t)NP * 64;        // NP f32
    ushort_t* stimT   = (ushort_t*)(attf + NP);               // NA*NP bf16
    ushort_t* numT    = stimT + (size_t)NA * NP;              // NA*NP bf16
    ushort_t* pnT     = numT + (size_t)NA * NP;               // NA*NP bf16

    setup_all<<<448, 256, 0, stream>>>(stim, pscale, pasig, pagain, pssf, psff,
                                       gxn_all, gyT_all, attf, stimT);

    const float* gx0 = gxn_all;
    const float* gx1 = gxn_all + (size_t)NP * 64;
    const float* gx2 = gxn_all + 2 * (size_t)NP * 64;
    const float* gy0 = gyT_all;
    const float* gy1 = gyT_all + (size_t)64 * NP;
    const float* gy2 = gyT_all + 2 * (size_t)64 * NP;

    dim3 g(64, 4);
    field_gemm<0><<<g, 512, 0, stream>>>(gx0, gy0, stimT, attf, nullptr,
                                         num, nullptr, numT);
    field_gemm<1><<<g, 512, 0, stream>>>(gx1, gy1, numT, attf, num,
                                         surr, pn, pnT);
    field_gemm<2><<<g, 512, 0, stream>>>(gx2, gy2, pnT, attf, nullptr,
                                         pv, nullptr, nullptr);
}